// Round 12
// baseline (91.682 us; speedup 1.0000x reference)
//
#include <hip/hip_runtime.h>
#include <hip/hip_bf16.h>

// NT-Xent loss: B=4096, D=128, TEMP=0.5, N2=8192.
// loss = mean_i [ log sum_{j!=i} exp(2*sim_ij) - 2*pos_i ]
// sim = zn zn^T (bf16 MFMA), pos_i = fp32 cosine(z_i, z_{i^B}).
// Self-diagonal handled by rowsum init = -exp2(sii_scaled).
//
// R12: SYMMETRY. Six schedule/register rounds left sim at ~33us (floor
// ~9): change the algorithm. sim is symmetric -> compute only triangular
// panel pairs (64 panels x 128 rows, 2080 blocks). Off-diag tile (I,J):
// row-sums -> panel I, COLUMN-sums -> panel J (exp(sim_ij) feeds both
// rowsum_i and rowsum_j). Diagonal tiles: row-sums only. Halves MFMA,
// exp, and LDS-read work. Col-sums: per k-tile all 8 of a lane's exp
// values share one column -> scalar cvk + 2 shfl_xor (quad reduce) +
// ds_write to csum[wave][col] (own row, no race), one final barrier,
// 128 col atomics per off-diag block. B staging identical to R11
// (TW=64, NRD=2, same verified swizzle - all block-local indices).

#define BB 4096
#define N2 8192
#define DD 128
#define NPAN 64            // panels of 128 rows
#define PANROWS 128
#define CW 128             // cols per block (one panel)
#define TW 64              // cols staged per round (4 col-tiles, 16 KB)
#define NRD 2              // rounds
#define NBLK2 (NPAN * (NPAN + 1) / 2)   // 2080 triangular blocks
#define BUFBYTES (TW * 16 * 16)         // 16384 B per LDS buffer

// sqrt(2*log2(e)): zn scaled by this => A.B = 2*log2(e)*sim, so
// exp(2*sim) = exp2(A.B) directly.
#define SCALE 1.69864360f

#if __has_builtin(__builtin_amdgcn_exp2f)
#define EXP2F(x) __builtin_amdgcn_exp2f(x)
#else
#define EXP2F(x) __expf((x) * 0.6931471805599453f)
#endif

using bf16 = __hip_bfloat16;
typedef __attribute__((ext_vector_type(8))) short short8;   // MFMA A/B frag
typedef __attribute__((ext_vector_type(4))) float float4v;  // MFMA C/D frag

// ---------------- Kernel 1: per-pair normalize, scale, cast bf16 ----------
__global__ __launch_bounds__(256) void ntx_norm_kernel(
    const float* __restrict__ zi, const float* __restrict__ zj,
    bf16* __restrict__ zn, float* __restrict__ rowsum, float* __restrict__ pos) {
  const int wave = threadIdx.x >> 6;
  const int lane = threadIdx.x & 63;
  const int pair = blockIdx.x * 4 + wave;   // 1024 blocks, 4 pairs/block
  float2 v = ((const float2*)(zi + (size_t)pair * DD))[lane];
  float2 w = ((const float2*)(zj + (size_t)pair * DD))[lane];
  float s1 = v.x * v.x + v.y * v.y;
  float s2 = w.x * w.x + w.y * w.y;
  float s3 = v.x * w.x + v.y * w.y;
  #pragma unroll
  for (int o = 32; o > 0; o >>= 1) {
    s1 += __shfl_xor(s1, o);
    s2 += __shfl_xor(s2, o);
    s3 += __shfl_xor(s3, o);
  }
  float nv = fmaxf(sqrtf(s1), 1e-8f);
  float nw = fmaxf(sqrtf(s2), 1e-8f);
  float rv = SCALE / nv, rw = SCALE / nw;   // scale folded into zn
  bf16 bx = __float2bfloat16(v.x * rv);
  bf16 by = __float2bfloat16(v.y * rv);
  bf16 cx = __float2bfloat16(w.x * rw);
  bf16 cy = __float2bfloat16(w.y * rw);
  __hip_bfloat162 h2; h2.x = bx; h2.y = by;
  __hip_bfloat162 g2; g2.x = cx; g2.y = cy;
  ((__hip_bfloat162*)(zn + (size_t)pair * DD))[lane] = h2;
  ((__hip_bfloat162*)(zn + (size_t)(pair + BB) * DD))[lane] = g2;
  // self-dot in the SAME scaled bf16 precision the MFMA will see
  float fx = __bfloat162float(bx), fy = __bfloat162float(by);
  float gx = __bfloat162float(cx), gy = __bfloat162float(cy);
  float sii = fx * fx + fy * fy;            // = 2log2e * sim_ii (scaled)
  float sjj = gx * gx + gy * gy;
  #pragma unroll
  for (int o = 32; o > 0; o >>= 1) {
    sii += __shfl_xor(sii, o);
    sjj += __shfl_xor(sjj, o);
  }
  if (lane == 0) {
    float c = s3 / (nv * nw);               // fp32 positive-pair cosine
    rowsum[pair]      = -EXP2F(sii);        // cancels diagonal term
    rowsum[pair + BB] = -EXP2F(sjj);
    pos[pair]      = c;
    pos[pair + BB] = c;
  }
}

// ---------------- Kernel 2: triangular sim + sum-exp -----------------------
// grid 2080 = panel pairs (I<=J). Block 256 = 4 waves; wave owns 32 rows
// (2 row-tiles) of panel I; block covers 128 cols = panel J. Per round:
// stage 64 cols of B (reg->LDS, pre-swizzled src, loads EARLY), compute
// 4 col-tiles, accumulate row-sums in regs and col-sums via quad-reduce
// into csum LDS strip, ONE barrier, flip.
__global__ __launch_bounds__(256) void ntx_sim_kernel(
    const bf16* __restrict__ zn, float* __restrict__ rowsum) {
  const int tid  = threadIdx.x;
  const int wave = tid >> 6;
  const int lane = tid & 63;
  const int quad = lane >> 4;
  const int l15  = lane & 15;
  const char* zb  = (const char*)zn;
  const short* zs = (const short*)zn;

  __shared__ float4 lds[2][TW * 16];   // 2 x 16 KB double buffer
  __shared__ float csum[4][CW];        // per-wave col-sum strips (2 KB)

  // triangular decode: block -> (I, J), I <= J
  int I = 0, rem = blockIdx.x;
  while (rem >= NPAN - I) { rem -= NPAN - I; I++; }
  const int J = I + rem;
  const bool diag = (I == J);

  const int rowBase  = I * PANROWS + wave * 32;
  const int colBase0 = J * PANROWS;

  // Staging map (block-local, identical to R11): chunk p holds global
  // 16B-chunk (slot ^ (g&7)) of block-local col-row g (g=p>>4, slot=p&15)
  // -> swizzled ds_read_b128 is uniform 8 dwords/bank.
  const int g0 = tid >> 4;
  const int sw = ((tid & 15) ^ (g0 & 7)) << 4;
  const char* srcb = zb + (size_t)(colBase0 + g0) * 256 + sw;

  // prologue: stage round 0 (cols 0..63 of panel J)
  float4 p0 = *(const float4*)(srcb);
  float4 p1 = *(const float4*)(srcb + 4096);
  float4 p2 = *(const float4*)(srcb + 8192);
  float4 p3 = *(const float4*)(srcb + 12288);

  // A fragments: 2 row-tiles x 4 K-chunks (32 VGPRs)
  short8 a[2][4];
  #pragma unroll
  for (int t = 0; t < 2; t++) {
    const short* ap = zs + (size_t)(rowBase + t * 16 + l15) * DD + quad * 8;
    #pragma unroll
    for (int c = 0; c < 4; c++) a[t][c] = *(const short8*)(ap + c * 32);
  }
  // keep A resident (R10 pathology guard)
  asm volatile("" : "+v"(a[0][0]), "+v"(a[0][1]), "+v"(a[0][2]), "+v"(a[0][3]),
                    "+v"(a[1][0]), "+v"(a[1][1]), "+v"(a[1][2]), "+v"(a[1][3]));

  float rs[2][4];
  #pragma unroll
  for (int t = 0; t < 2; t++)
    #pragma unroll
    for (int r = 0; r < 4; r++) rs[t][r] = 0.0f;

  lds[0][tid] = p0;
  lds[0][tid + 256] = p1;
  lds[0][tid + 512] = p2;
  lds[0][tid + 768] = p3;
  __syncthreads();

  char* ldsbase = (char*)&lds[0][0];
  int cur = 0;
  #pragma unroll 1
  for (int rd = 0; rd < NRD; rd++) {
    float4 t0, t1, t2, t3;
    const bool pf = (rd + 1 < NRD);
    if (pf) {
      const char* sb = srcb + (size_t)(rd + 1) * (TW * 256);
      t0 = *(const float4*)(sb);
      t1 = *(const float4*)(sb + 4096);
      t2 = *(const float4*)(sb + 8192);
      t3 = *(const float4*)(sb + 12288);
    }

    const char* lb = ldsbase + cur * BUFBYTES;
    #pragma unroll
    for (int k = 0; k < 4; k++) {           // 4 col-tiles per round
      short8 b[4];
      #pragma unroll
      for (int c = 0; c < 4; c++) {
        const int off = k * 4096 + l15 * 256 +
                        ((((c * 4 + quad) ^ (l15 & 7))) << 4);
        b[c] = *(const short8*)(lb + off);
      }
      float cvk = 0.0f;   // this lane's col (k*16+l15) partial sum
      #pragma unroll
      for (int t = 0; t < 2; t++) {
        float4v acc = {0.f, 0.f, 0.f, 0.f};
        acc = __builtin_amdgcn_mfma_f32_16x16x32_bf16(a[t][0], b[0], acc, 0, 0, 0);
        acc = __builtin_amdgcn_mfma_f32_16x16x32_bf16(a[t][1], b[1], acc, 0, 0, 0);
        acc = __builtin_amdgcn_mfma_f32_16x16x32_bf16(a[t][2], b[2], acc, 0, 0, 0);
        acc = __builtin_amdgcn_mfma_f32_16x16x32_bf16(a[t][3], b[3], acc, 0, 0, 0);
        // C/D: col = l15, row = quad*4 + r [m89/m91]; acc = 2log2e*sim.
        #pragma unroll
        for (int r = 0; r < 4; r++) {
          float e = EXP2F(acc[r]);
          rs[t][r] += e;
          cvk += e;
        }
      }
      // col-sum over the wave's 32 rows: reduce across quads
      cvk += __shfl_xor(cvk, 16);
      cvk += __shfl_xor(cvk, 32);
      if (quad == 0) csum[wave][rd * TW + k * 16 + l15] = cvk;
    }

    if (pf) {
      lds[cur ^ 1][tid] = t0;
      lds[cur ^ 1][tid + 256] = t1;
      lds[cur ^ 1][tid + 512] = t2;
      lds[cur ^ 1][tid + 768] = t3;
      __syncthreads();
      cur ^= 1;
    }
  }

  // row-sums: reduce across the 16 lanes sharing each row, one atomic each
  #pragma unroll
  for (int t = 0; t < 2; t++) {
    #pragma unroll
    for (int r = 0; r < 4; r++) {
      float s = rs[t][r];
      s += __shfl_xor(s, 1);
      s += __shfl_xor(s, 2);
      s += __shfl_xor(s, 4);
      s += __shfl_xor(s, 8);
      if (l15 == 0)
        atomicAdd(&rowsum[rowBase + t * 16 + quad * 4 + r], s);
    }
  }

  // col-sums -> panel J rows (off-diagonal blocks only; diagonal blocks'
  // col-sums would double-count their symmetric tile)
  __syncthreads();   // all csum writes visible
  if (!diag && tid < CW) {
    float s = csum[0][tid] + csum[1][tid] + csum[2][tid] + csum[3][tid];
    atomicAdd(&rowsum[colBase0 + tid], s);
  }
}

// ---------------- Kernel 3: finalize --------------------------------------
__global__ __launch_bounds__(1024) void ntx_finalize_kernel(
    const float* __restrict__ rowsum, const float* __restrict__ pos,
    float* __restrict__ out) {
  float s = 0.f;
  for (int i = threadIdx.x; i < N2; i += 1024)
    s += __logf(rowsum[i]) - 2.0f * pos[i];
  #pragma unroll
  for (int o = 32; o > 0; o >>= 1) s += __shfl_xor(s, o);
  __shared__ float sm[16];
  const int wave = threadIdx.x >> 6;
  const int lane = threadIdx.x & 63;
  if (lane == 0) sm[wave] = s;
  __syncthreads();
  if (threadIdx.x == 0) {
    float t = 0.f;
    #pragma unroll
    for (int i = 0; i < 16; i++) t += sm[i];
    out[0] = t / (float)N2;
  }
}

extern "C" void kernel_launch(void* const* d_in, const int* in_sizes, int n_in,
                              void* d_out, int out_size, void* d_ws, size_t ws_size,
                              hipStream_t stream) {
  const float* zi = (const float*)d_in[0];
  const float* zj = (const float*)d_in[1];
  float* out = (float*)d_out;

  char* ws = (char*)d_ws;
  bf16* zn = (bf16*)ws;                                   // 8192*128*2 = 2 MB
  float* rowsum = (float*)(ws + (size_t)N2 * DD * 2);     // 32 KB
  float* pos = rowsum + N2;                               // 32 KB

  ntx_norm_kernel<<<BB / 4, 256, 0, stream>>>(zi, zj, zn, rowsum, pos);
  ntx_sim_kernel<<<NBLK2, 256, 0, stream>>>(zn, rowsum);
  ntx_finalize_kernel<<<1, 1024, 0, stream>>>(rowsum, pos, out);
}